// Round 11
// baseline (702.429 us; speedup 1.0000x reference)
//
#include <hip/hip_runtime.h>
#include <hip/hip_bf16.h>

#define N_NODES 50000
#define N_EDGES 800000
#define IN_FEAT 100
#define OUT_FEAT 100
#define NUM_RELS 200
#define NUM_HEADS 3

#define KP 128          // padded K (100 -> 128)
#define NPH 112         // per-head padded N for MFMA tiling (7*16)
#define MB  128         // node-rows per block (loop_gemm)
#define NT_O 7          // NPH/16
#define WPB 16          // waves per feat block (1024 threads)
#define MSGW 100        // msg row width (ushorts) = 200 B
#define BROWS 312       // compact B rows: 3*100 + 12 guard
#define HSTRIDE 25600   // bytes per head in compact B (100 rows * 256 B)

// ---- workspace layout (bytes) ----
#define WS_B       0u           // compact fc_w^T bf16 image: 79872
#define WS_LW      86016u       // loop_w^T bf16 image (linear): 28672
#define WS_CNT     114688u      // 50176 ints
#define WS_OFFS    315392u
#define WS_CURSOR  516096u
#define WS_BSUM    716800u      // 64 ints
#define WS_SLOT    717056u      // slotmap[e]: 800000 ints
#define WS_MSG     7117056u     // bf16 msg rows, 100 ushorts (200 B) each, slot order
#define WS_NEEDED  167117056u
#define NNODES_PAD 50176        // 49*1024

typedef __attribute__((ext_vector_type(8))) short short8;
typedef __attribute__((ext_vector_type(4))) float f32x4;

__device__ __forceinline__ unsigned short f2bf(float f) {
    unsigned u = __builtin_bit_cast(unsigned, f);
    unsigned r = u + 0x7FFFu + ((u >> 16) & 1u);
    return (unsigned short)(r >> 16);
}
__device__ __forceinline__ float bf2f(unsigned hs) {
    return __builtin_bit_cast(float, hs << 16);
}

// ---------------------------------------------------------------------------
// Compact B = fc_w^T bf16: 312 rows of 256 B. Row n (= head*100 + nl for
// n<300; zero guard rows for n>=300), XOR-swizzled:
// granule g at byte n*256 + ((g*16) ^ ((nl&7)<<4)); elem j in [0,8):
// k = kt*32 + (j>>2)*16 + g4*4 + (j&3). Padded-row reads (nl>=100) land in
// next head's rows / guard -> garbage feeds only discarded columns.
// ---------------------------------------------------------------------------
__global__ __launch_bounds__(256) void build_B(const float* __restrict__ fc_w,
                                               unsigned short* __restrict__ Bws) {
    int idx = blockIdx.x * 256 + threadIdx.x;     // granule id: n*16 + g
    if (idx >= BROWS * 16) return;
    int n = idx >> 4, g = idx & 15;
    int head = n / 100, nl = n - head * 100;      // head==3 -> guard rows
    int kt = g >> 2, g4 = g & 3;
    unsigned p[4] = {0u, 0u, 0u, 0u};
    if (n < 300) {
#pragma unroll
        for (int half = 0; half < 2; ++half) {
#pragma unroll
            for (int jp = 0; jp < 2; ++jp) {
                int k_lo = kt * 32 + half * 16 + g4 * 4 + jp * 2;
                int k_hi = k_lo + 1;
                float vlo = (k_lo < IN_FEAT)
                          ? fc_w[k_lo * (OUT_FEAT * NUM_HEADS) + head * OUT_FEAT + nl] : 0.f;
                float vhi = (k_hi < IN_FEAT)
                          ? fc_w[k_hi * (OUT_FEAT * NUM_HEADS) + head * OUT_FEAT + nl] : 0.f;
                p[half * 2 + jp] = (unsigned)f2bf(vlo) | ((unsigned)f2bf(vhi) << 16);
            }
        }
    }
    unsigned off = (unsigned)(n * 256) + (((unsigned)(g * 16)) ^ (((unsigned)(nl & 7)) << 4));
    *reinterpret_cast<int4*>(reinterpret_cast<char*>(Bws) + off) =
        make_int4((int)p[0], (int)p[1], (int)p[2], (int)p[3]);
}

// loop_w^T bf16 image, LINEAR (read from L2 by loop_gemm fragments)
__global__ __launch_bounds__(256) void build_LW(const float* __restrict__ loop_w,
                                                unsigned short* __restrict__ LWws) {
    int idx = blockIdx.x * 256 + threadIdx.x;
    if (idx >= NPH * 16) return;
    int nl = idx >> 4, g = idx & 15;
    int kt = g >> 2, g4 = g & 3;
    unsigned p[4];
#pragma unroll
    for (int half = 0; half < 2; ++half) {
#pragma unroll
        for (int jp = 0; jp < 2; ++jp) {
            int k_lo = kt * 32 + half * 16 + g4 * 4 + jp * 2;
            int k_hi = k_lo + 1;
            float vlo = (k_lo < IN_FEAT && nl < OUT_FEAT) ? loop_w[k_lo * OUT_FEAT + nl] : 0.f;
            float vhi = (k_hi < IN_FEAT && nl < OUT_FEAT) ? loop_w[k_hi * OUT_FEAT + nl] : 0.f;
            p[half * 2 + jp] = (unsigned)f2bf(vlo) | ((unsigned)f2bf(vhi) << 16);
        }
    }
    reinterpret_cast<int4*>(LWws)[idx] = make_int4((int)p[0], (int)p[1], (int)p[2], (int)p[3]);
}

// ---------------------------------------------------------------------------
// Self-loop GEMM: out = h @ loop_w. Zero LDS/barriers; LW from L2.
// ---------------------------------------------------------------------------
__global__ __launch_bounds__(512, 2) void loop_gemm(const float* __restrict__ h,
                                                    const unsigned short* __restrict__ LWimg,
                                                    float* __restrict__ out) {
    const int tid = threadIdx.x;
    const int wave = tid >> 6, lane = tid & 63;
    const int lrow = lane & 15, lk = lane >> 4;
    const int rbase = blockIdx.x * MB;
    const int grow = rbase + wave * 16 + lrow;
    const bool ok = grow < N_NODES;
    const float* ap = h + (size_t)grow * IN_FEAT;

    short8 afrag[4];
#pragma unroll
    for (int kt = 0; kt < 4; ++kt) {
        int k0 = kt * 32 + lk * 4, k1 = k0 + 16;
        float4 va = (ok && k0 + 4 <= IN_FEAT) ? *reinterpret_cast<const float4*>(ap + k0)
                                              : make_float4(0.f, 0.f, 0.f, 0.f);
        float4 vb = (ok && k1 + 4 <= IN_FEAT) ? *reinterpret_cast<const float4*>(ap + k1)
                                              : make_float4(0.f, 0.f, 0.f, 0.f);
        afrag[kt][0] = (short)f2bf(va.x); afrag[kt][1] = (short)f2bf(va.y);
        afrag[kt][2] = (short)f2bf(va.z); afrag[kt][3] = (short)f2bf(va.w);
        afrag[kt][4] = (short)f2bf(vb.x); afrag[kt][5] = (short)f2bf(vb.y);
        afrag[kt][6] = (short)f2bf(vb.z); afrag[kt][7] = (short)f2bf(vb.w);
    }

#pragma unroll
    for (int nt = 0; nt < NT_O; ++nt) {
        f32x4 acc = (f32x4){0.f, 0.f, 0.f, 0.f};
#pragma unroll
        for (int kt = 0; kt < 4; ++kt) {
            short8 bfrag = *reinterpret_cast<const short8*>(
                LWimg + ((nt * 16 + lrow) * KP + kt * 32 + lk * 8));
            acc = __builtin_amdgcn_mfma_f32_16x16x32_bf16(afrag[kt], bfrag, acc, 0, 0, 0);
        }
        int o = nt * 16 + lrow;
        if (o < OUT_FEAT) {
#pragma unroll
            for (int r = 0; r < 4; ++r) {
                int crow = rbase + wave * 16 + lk * 4 + r;
                if (crow < N_NODES) out[(size_t)crow * OUT_FEAT + o] = acc[r];
            }
        }
    }
}

// ---------------------------------------------------------------------------
// CSR construction
// ---------------------------------------------------------------------------
__global__ __launch_bounds__(512) void hist_kernel(const int* __restrict__ dst,
                                                   int* __restrict__ cnt) {
    int e = blockIdx.x * 512 + threadIdx.x;
    if (e < N_EDGES) atomicAdd(&cnt[dst[e]], 1);
}

__global__ __launch_bounds__(1024) void scan1(const int* __restrict__ cnt,
                                              int* __restrict__ offs,
                                              int* __restrict__ bsum) {
    __shared__ int s[1024];
    int i = blockIdx.x * 1024 + threadIdx.x;
    int v = (i < N_NODES) ? cnt[i] : 0;
    s[threadIdx.x] = v;
    __syncthreads();
    for (int d = 1; d < 1024; d <<= 1) {
        int t = (threadIdx.x >= d) ? s[threadIdx.x - d] : 0;
        __syncthreads();
        s[threadIdx.x] += t;
        __syncthreads();
    }
    offs[i] = s[threadIdx.x] - v;
    if (threadIdx.x == 1023) bsum[blockIdx.x] = s[1023];
}

__global__ __launch_bounds__(64) void scan2(int* __restrict__ bsum) {
    __shared__ int s[64];
    int v = (threadIdx.x < NNODES_PAD / 1024) ? bsum[threadIdx.x] : 0;
    s[threadIdx.x] = v;
    __syncthreads();
    for (int d = 1; d < 64; d <<= 1) {
        int t = (threadIdx.x >= d) ? s[threadIdx.x - d] : 0;
        __syncthreads();
        s[threadIdx.x] += t;
        __syncthreads();
    }
    bsum[threadIdx.x] = s[threadIdx.x] - v;
}

__global__ __launch_bounds__(1024) void scan3(int* __restrict__ offs,
                                              const int* __restrict__ bsum,
                                              int* __restrict__ cursor) {
    int i = blockIdx.x * 1024 + threadIdx.x;
    int v = offs[i] + bsum[blockIdx.x];
    offs[i] = v;
    cursor[i] = v;
}

// slotmap[e]=p (scatter map for feat)
__global__ __launch_bounds__(512) void scatter_kernel(const int* __restrict__ dst,
                                                      int* __restrict__ cursor,
                                                      int* __restrict__ slotmap) {
    int e = blockIdx.x * 512 + threadIdx.x;
    if (e < N_EDGES) {
        int p = atomicAdd(&cursor[dst[e]], 1);
        slotmap[e] = p;
    }
}

// ---------------------------------------------------------------------------
// feat kernel v11: 1024 threads (16 waves share one 79872 B persistent B tile
// -> 16 waves/CU at 1 block/CU, reg cap 128). Natural edge order, A+rel+src+
// dst prefetched one tile ahead; feat initialized with h[src]*w[rel] (56
// quarter-wave-segment loads issued BEFORE the MFMA loop, completing under
// its shadow); full message (h*w + attfeat)*norm scattered bf16 to dst-sorted
// slots. r9 body (88 regs) + ~25 -> fits the 128 cap without spill.
// ---------------------------------------------------------------------------
template<bool TOWS>
__global__ __launch_bounds__(1024, 1) void feat_kernel(
        const float* __restrict__ efeat, const int* __restrict__ rel,
        const unsigned short* __restrict__ Bimg, const float* __restrict__ attn,
        const float* __restrict__ h, const float* __restrict__ weight,
        const float* __restrict__ norm, const int* __restrict__ src,
        const int* __restrict__ dst, const int* __restrict__ slotmap,
        float* __restrict__ out, unsigned short* __restrict__ msgws,
        int ntiles) {   // ntiles = N_EDGES / 16

    __shared__ __align__(16) unsigned short Blds[BROWS * 128];   // 79872 B

    const int tid = threadIdx.x;
    {
        const int4* sp = reinterpret_cast<const int4*>(Bimg);
        int4* dp = reinterpret_cast<int4*>(Blds);
        for (int i = tid; i < BROWS * 128 / 8; i += 1024) dp[i] = sp[i];
    }
    __syncthreads();   // the only barrier

    const int wave = tid >> 6, lane = tid & 63;
    const int lrow = lane & 15, lk = lane >> 4;
    const int gstride = gridDim.x * WPB;
    int tile = blockIdx.x * WPB + wave;
    if (tile >= ntiles) return;

    const char* Bc = reinterpret_cast<const char*>(Blds);
    int bkt[4];
#pragma unroll
    for (int kt = 0; kt < 4; ++kt)
        bkt[kt] = lrow * 256 + ((kt * 64 + lk * 16) ^ ((lrow & 7) << 4));

    float4 pa[8];
    int prl[4], psr[4], pdd[4];

    auto prefetch = [&](int t) {
        int eb = t * 16;
        const float* ap = efeat + (size_t)(eb + lrow) * IN_FEAT;
#pragma unroll
        for (int kt = 0; kt < 4; ++kt) {
            int k0 = kt * 32 + lk * 4, k1 = k0 + 16;
            pa[kt * 2]     = (k0 + 4 <= IN_FEAT) ? *reinterpret_cast<const float4*>(ap + k0)
                                                 : make_float4(0.f, 0.f, 0.f, 0.f);
            pa[kt * 2 + 1] = (k1 + 4 <= IN_FEAT) ? *reinterpret_cast<const float4*>(ap + k1)
                                                 : make_float4(0.f, 0.f, 0.f, 0.f);
        }
        const int* rp = rel + eb + lk * 4;
        const int* sp = src + eb + lk * 4;
        const int* dp = dst + eb + lk * 4;
#pragma unroll
        for (int r = 0; r < 4; ++r) { prl[r] = rp[r]; psr[r] = sp[r]; pdd[r] = dp[r]; }
    };

    prefetch(tile);

    while (true) {
        const int cur = tile;
        const int tb = cur * 16;

        // ---- consume prefetched A ----
        short8 afrag[4];
#pragma unroll
        for (int kt = 0; kt < 4; ++kt) {
            float4 va = pa[kt * 2], vb = pa[kt * 2 + 1];
            afrag[kt][0] = (short)f2bf(va.x); afrag[kt][1] = (short)f2bf(va.y);
            afrag[kt][2] = (short)f2bf(va.z); afrag[kt][3] = (short)f2bf(va.w);
            afrag[kt][4] = (short)f2bf(vb.x); afrag[kt][5] = (short)f2bf(vb.y);
            afrag[kt][6] = (short)f2bf(vb.z); afrag[kt][7] = (short)f2bf(vb.w);
        }
        int aoff[4], hoff[4], woff[4];
        float nm[4];
#pragma unroll
        for (int r = 0; r < 4; ++r) {
            aoff[r] = prl[r] * (NUM_HEADS * OUT_FEAT);
            woff[r] = prl[r] * OUT_FEAT;
            hoff[r] = psr[r] * IN_FEAT;
            nm[r]   = norm[pdd[r]];
        }
        int slot_r[4], dd_r[4];
        if (TOWS) {
#pragma unroll
            for (int r = 0; r < 4; ++r) slot_r[r] = slotmap[tb + lk * 4 + r];
        } else {
#pragma unroll
            for (int r = 0; r < 4; ++r) dd_r[r] = pdd[r];
        }

        // ---- prefetch next tile ----
        int next = tile + gstride;
        bool more = next < ntiles;
        prefetch(more ? next : cur);

        // ---- feat init = h[src] * w[rel]; loads complete under MFMA shadow ----
        float feat[NT_O][4];
#pragma unroll
        for (int nt = 0; nt < NT_O; ++nt) {
            int o = nt * 16 + lrow;
#pragma unroll
            for (int r = 0; r < 4; ++r)
                feat[nt][r] = (o < OUT_FEAT) ? h[hoff[r] + o] * weight[woff[r] + o] : 0.f;
        }

        // ---- 3 heads x 7 col-tiles x K=128, B from LDS ----
#pragma unroll 1
        for (int hh = 0; hh < NUM_HEADS; ++hh) {
            const char* Bh = Bc + hh * HSTRIDE;
#pragma unroll
            for (int nt = 0; nt < NT_O; ++nt) {
                f32x4 acc = (f32x4){0.f, 0.f, 0.f, 0.f};
#pragma unroll
                for (int kt = 0; kt < 4; ++kt) {
                    short8 bfrag = *reinterpret_cast<const short8*>(
                        Bh + bkt[kt] + nt * 4096);
                    acc = __builtin_amdgcn_mfma_f32_16x16x32_bf16(afrag[kt], bfrag, acc, 0, 0, 0);
                }
                int o = nt * 16 + lrow;
                if (o < OUT_FEAT) {
                    int oo = hh * OUT_FEAT + o;
#pragma unroll
                    for (int r = 0; r < 4; ++r) {
                        float v = acc[r] * attn[aoff[r] + oo];
                        feat[nt][r] += (v > 0.f) ? v : 0.2f * v;
                    }
                }
            }
        }

        if (TOWS) {
            // complete message * norm, scattered to dst-sorted slots
#pragma unroll
            for (int nt = 0; nt < NT_O; ++nt) {
                int o = nt * 16 + lrow;
                if (o < OUT_FEAT) {
#pragma unroll
                    for (int r = 0; r < 4; ++r)
                        msgws[(size_t)slot_r[r] * MSGW + o] = f2bf(feat[nt][r] * nm[r]);
                }
            }
        } else {
            // fallback: atomic scatter-add of the complete message
#pragma unroll
            for (int nt = 0; nt < NT_O; ++nt) {
                int o = nt * 16 + lrow;
                if (o < OUT_FEAT) {
#pragma unroll
                    for (int r = 0; r < 4; ++r)
                        atomicAdd(&out[(size_t)dd_r[r] * OUT_FEAT + o],
                                  feat[nt][r] * nm[r]);
                }
            }
        }

        if (!more) break;
        tile = next;
    }
}

// ---------------------------------------------------------------------------
// agg kernel: one wave per node; msg rows CONTIGUOUS in slot order -> pure
// streaming segmented sum (norm already folded). out += sum. No gathers.
// ---------------------------------------------------------------------------
__global__ __launch_bounds__(256, 4) void agg_kernel(
        const unsigned short* __restrict__ msgws, const int* __restrict__ offs,
        const int* __restrict__ cnt, float* __restrict__ out) {
    int wv = threadIdx.x >> 6, lane = threadIdx.x & 63;
    int n = blockIdx.x * 4 + wv;
    if (n >= N_NODES) return;
    int start = offs[n], deg = cnt[n];
    if (deg == 0 || lane >= OUT_FEAT / 2) return;
    const unsigned* mp = reinterpret_cast<const unsigned*>(msgws);
    float ax = 0.f, ay = 0.f;
    int k = start, end = start + deg;
    for (; k + 4 <= end; k += 4) {
        unsigned u0 = mp[(size_t)k * (MSGW / 2) + lane];
        unsigned u1 = mp[(size_t)(k + 1) * (MSGW / 2) + lane];
        unsigned u2 = mp[(size_t)(k + 2) * (MSGW / 2) + lane];
        unsigned u3 = mp[(size_t)(k + 3) * (MSGW / 2) + lane];
        ax += bf2f(u0 & 0xffffu) + bf2f(u1 & 0xffffu) + bf2f(u2 & 0xffffu) + bf2f(u3 & 0xffffu);
        ay += bf2f(u0 >> 16) + bf2f(u1 >> 16) + bf2f(u2 >> 16) + bf2f(u3 >> 16);
    }
    for (; k < end; ++k) {
        unsigned u0 = mp[(size_t)k * (MSGW / 2) + lane];
        ax += bf2f(u0 & 0xffffu);
        ay += bf2f(u0 >> 16);
    }
    float2* op = reinterpret_cast<float2*>(out + (size_t)n * OUT_FEAT) + lane;
    float2 curv = *op;
    curv.x += ax; curv.y += ay;
    *op = curv;
}

extern "C" void kernel_launch(void* const* d_in, const int* in_sizes, int n_in,
                              void* d_out, int out_size, void* d_ws, size_t ws_size,
                              hipStream_t stream) {
    const float* h      = (const float*)d_in[0];
    const float* efeat  = (const float*)d_in[1];
    const float* norm   = (const float*)d_in[2];
    const float* weight = (const float*)d_in[3];
    const float* attn   = (const float*)d_in[4];
    const float* fc_w   = (const float*)d_in[5];
    const float* loop_w = (const float*)d_in[6];
    const int*   rel    = (const int*)d_in[7];
    const int*   src    = (const int*)d_in[8];
    const int*   dst    = (const int*)d_in[9];
    float* out = (float*)d_out;

    char* ws = (char*)d_ws;
    unsigned short* Bimg  = (unsigned short*)(ws + WS_B);
    unsigned short* LWimg = (unsigned short*)(ws + WS_LW);
    int* cnt     = (int*)(ws + WS_CNT);
    int* offs    = (int*)(ws + WS_OFFS);
    int* cursor  = (int*)(ws + WS_CURSOR);
    int* bsum    = (int*)(ws + WS_BSUM);
    int* slotmap = (int*)(ws + WS_SLOT);
    unsigned short* msgws = (unsigned short*)(ws + WS_MSG);

    build_B<<<(BROWS * 16 + 255) / 256, 256, 0, stream>>>(fc_w, Bimg);
    build_LW<<<(NPH * 16 + 255) / 256, 256, 0, stream>>>(loop_w, LWimg);
    loop_gemm<<<(N_NODES + MB - 1) / MB, 512, 0, stream>>>(h, LWimg, out);

    const int ntiles = N_EDGES / 16;   // 50000

    if (ws_size >= (size_t)WS_NEEDED) {
        hipMemsetAsync(cnt, 0, NNODES_PAD * sizeof(int), stream);
        hist_kernel<<<(N_EDGES + 511) / 512, 512, 0, stream>>>(dst, cnt);
        scan1<<<NNODES_PAD / 1024, 1024, 0, stream>>>(cnt, offs, bsum);
        scan2<<<1, 64, 0, stream>>>(bsum);
        scan3<<<NNODES_PAD / 1024, 1024, 0, stream>>>(offs, bsum, cursor);
        scatter_kernel<<<(N_EDGES + 511) / 512, 512, 0, stream>>>(dst, cursor, slotmap);

        feat_kernel<true><<<256, 1024, 0, stream>>>(
            efeat, rel, Bimg, attn, h, weight, norm, src, dst, slotmap,
            out, msgws, ntiles);
        agg_kernel<<<(N_NODES + 3) / 4, 256, 0, stream>>>(msgws, offs, cnt, out);
    } else {
        feat_kernel<false><<<256, 1024, 0, stream>>>(
            efeat, rel, Bimg, attn, h, weight, norm, src, dst, nullptr,
            out, msgws, ntiles);
    }
}

// Round 12
// 401.761 us; speedup vs baseline: 1.7484x; 1.7484x over previous
//
#include <hip/hip_runtime.h>
#include <hip/hip_bf16.h>

#define N_NODES 50000
#define N_EDGES 800000
#define IN_FEAT 100
#define OUT_FEAT 100
#define NUM_RELS 200
#define NUM_HEADS 3

#define KP 128          // padded K (100 -> 128)
#define NPH 112         // per-head padded N for MFMA tiling (7*16)
#define MB  128         // node-rows per block (loop_gemm)
#define NT_O 7          // NPH/16
#define WPB 8           // waves per feat block (512 threads)
#define MSGW 100        // msg row width (ushorts) = 200 B
#define BROWS 312       // compact B rows: 3*100 + 12 guard
#define HSTRIDE 25600   // bytes per head in compact B (100 rows * 256 B)

// ---- workspace layout (bytes) ----
#define WS_B       0u           // compact fc_w^T bf16 image: 79872
#define WS_LW      86016u       // loop_w^T bf16 image (linear): 28672
#define WS_CNT     114688u      // 50176 ints
#define WS_OFFS    315392u
#define WS_CURSOR  516096u
#define WS_BSUM    716800u      // 64 ints
#define WS_SLOT    717056u      // slotmap[e]: 800000 ints
#define WS_MSG     7117056u     // bf16 msg rows, 100 ushorts (200 B) each, slot order
#define WS_NEEDED  167117056u
#define NNODES_PAD 50176        // 49*1024

typedef __attribute__((ext_vector_type(8))) short short8;
typedef __attribute__((ext_vector_type(4))) float f32x4;

__device__ __forceinline__ unsigned short f2bf(float f) {
    unsigned u = __builtin_bit_cast(unsigned, f);
    unsigned r = u + 0x7FFFu + ((u >> 16) & 1u);
    return (unsigned short)(r >> 16);
}
__device__ __forceinline__ float bf2f(unsigned hs) {
    return __builtin_bit_cast(float, hs << 16);
}

// ---------------------------------------------------------------------------
// Compact B = fc_w^T bf16: 312 rows of 256 B. Row n (= head*100 + nl for
// n<300; zero guard rows for n>=300), XOR-swizzled:
// granule g at byte n*256 + ((g*16) ^ ((nl&7)<<4)); elem j in [0,8):
// k = kt*32 + (j>>2)*16 + g4*4 + (j&3). Padded-row reads (nl>=100) land in
// next head's rows / guard -> garbage feeds only discarded columns.
// ---------------------------------------------------------------------------
__global__ __launch_bounds__(256) void build_B(const float* __restrict__ fc_w,
                                               unsigned short* __restrict__ Bws) {
    int idx = blockIdx.x * 256 + threadIdx.x;     // granule id: n*16 + g
    if (idx >= BROWS * 16) return;
    int n = idx >> 4, g = idx & 15;
    int head = n / 100, nl = n - head * 100;      // head==3 -> guard rows
    int kt = g >> 2, g4 = g & 3;
    unsigned p[4] = {0u, 0u, 0u, 0u};
    if (n < 300) {
#pragma unroll
        for (int half = 0; half < 2; ++half) {
#pragma unroll
            for (int jp = 0; jp < 2; ++jp) {
                int k_lo = kt * 32 + half * 16 + g4 * 4 + jp * 2;
                int k_hi = k_lo + 1;
                float vlo = (k_lo < IN_FEAT)
                          ? fc_w[k_lo * (OUT_FEAT * NUM_HEADS) + head * OUT_FEAT + nl] : 0.f;
                float vhi = (k_hi < IN_FEAT)
                          ? fc_w[k_hi * (OUT_FEAT * NUM_HEADS) + head * OUT_FEAT + nl] : 0.f;
                p[half * 2 + jp] = (unsigned)f2bf(vlo) | ((unsigned)f2bf(vhi) << 16);
            }
        }
    }
    unsigned off = (unsigned)(n * 256) + (((unsigned)(g * 16)) ^ (((unsigned)(nl & 7)) << 4));
    *reinterpret_cast<int4*>(reinterpret_cast<char*>(Bws) + off) =
        make_int4((int)p[0], (int)p[1], (int)p[2], (int)p[3]);
}

// loop_w^T bf16 image, LINEAR (read from L2 by loop_gemm fragments)
__global__ __launch_bounds__(256) void build_LW(const float* __restrict__ loop_w,
                                                unsigned short* __restrict__ LWws) {
    int idx = blockIdx.x * 256 + threadIdx.x;
    if (idx >= NPH * 16) return;
    int nl = idx >> 4, g = idx & 15;
    int kt = g >> 2, g4 = g & 3;
    unsigned p[4];
#pragma unroll
    for (int half = 0; half < 2; ++half) {
#pragma unroll
        for (int jp = 0; jp < 2; ++jp) {
            int k_lo = kt * 32 + half * 16 + g4 * 4 + jp * 2;
            int k_hi = k_lo + 1;
            float vlo = (k_lo < IN_FEAT && nl < OUT_FEAT) ? loop_w[k_lo * OUT_FEAT + nl] : 0.f;
            float vhi = (k_hi < IN_FEAT && nl < OUT_FEAT) ? loop_w[k_hi * OUT_FEAT + nl] : 0.f;
            p[half * 2 + jp] = (unsigned)f2bf(vlo) | ((unsigned)f2bf(vhi) << 16);
        }
    }
    reinterpret_cast<int4*>(LWws)[idx] = make_int4((int)p[0], (int)p[1], (int)p[2], (int)p[3]);
}

// ---------------------------------------------------------------------------
// Self-loop GEMM: out = h @ loop_w. Zero LDS/barriers; LW from L2.
// ---------------------------------------------------------------------------
__global__ __launch_bounds__(512, 2) void loop_gemm(const float* __restrict__ h,
                                                    const unsigned short* __restrict__ LWimg,
                                                    float* __restrict__ out) {
    const int tid = threadIdx.x;
    const int wave = tid >> 6, lane = tid & 63;
    const int lrow = lane & 15, lk = lane >> 4;
    const int rbase = blockIdx.x * MB;
    const int grow = rbase + wave * 16 + lrow;
    const bool ok = grow < N_NODES;
    const float* ap = h + (size_t)grow * IN_FEAT;

    short8 afrag[4];
#pragma unroll
    for (int kt = 0; kt < 4; ++kt) {
        int k0 = kt * 32 + lk * 4, k1 = k0 + 16;
        float4 va = (ok && k0 + 4 <= IN_FEAT) ? *reinterpret_cast<const float4*>(ap + k0)
                                              : make_float4(0.f, 0.f, 0.f, 0.f);
        float4 vb = (ok && k1 + 4 <= IN_FEAT) ? *reinterpret_cast<const float4*>(ap + k1)
                                              : make_float4(0.f, 0.f, 0.f, 0.f);
        afrag[kt][0] = (short)f2bf(va.x); afrag[kt][1] = (short)f2bf(va.y);
        afrag[kt][2] = (short)f2bf(va.z); afrag[kt][3] = (short)f2bf(va.w);
        afrag[kt][4] = (short)f2bf(vb.x); afrag[kt][5] = (short)f2bf(vb.y);
        afrag[kt][6] = (short)f2bf(vb.z); afrag[kt][7] = (short)f2bf(vb.w);
    }

#pragma unroll
    for (int nt = 0; nt < NT_O; ++nt) {
        f32x4 acc = (f32x4){0.f, 0.f, 0.f, 0.f};
#pragma unroll
        for (int kt = 0; kt < 4; ++kt) {
            short8 bfrag = *reinterpret_cast<const short8*>(
                LWimg + ((nt * 16 + lrow) * KP + kt * 32 + lk * 8));
            acc = __builtin_amdgcn_mfma_f32_16x16x32_bf16(afrag[kt], bfrag, acc, 0, 0, 0);
        }
        int o = nt * 16 + lrow;
        if (o < OUT_FEAT) {
#pragma unroll
            for (int r = 0; r < 4; ++r) {
                int crow = rbase + wave * 16 + lk * 4 + r;
                if (crow < N_NODES) out[(size_t)crow * OUT_FEAT + o] = acc[r];
            }
        }
    }
}

// ---------------------------------------------------------------------------
// CSR construction
// ---------------------------------------------------------------------------
__global__ __launch_bounds__(512) void hist_kernel(const int* __restrict__ dst,
                                                   int* __restrict__ cnt) {
    int e = blockIdx.x * 512 + threadIdx.x;
    if (e < N_EDGES) atomicAdd(&cnt[dst[e]], 1);
}

__global__ __launch_bounds__(1024) void scan1(const int* __restrict__ cnt,
                                              int* __restrict__ offs,
                                              int* __restrict__ bsum) {
    __shared__ int s[1024];
    int i = blockIdx.x * 1024 + threadIdx.x;
    int v = (i < N_NODES) ? cnt[i] : 0;
    s[threadIdx.x] = v;
    __syncthreads();
    for (int d = 1; d < 1024; d <<= 1) {
        int t = (threadIdx.x >= d) ? s[threadIdx.x - d] : 0;
        __syncthreads();
        s[threadIdx.x] += t;
        __syncthreads();
    }
    offs[i] = s[threadIdx.x] - v;
    if (threadIdx.x == 1023) bsum[blockIdx.x] = s[1023];
}

__global__ __launch_bounds__(64) void scan2(int* __restrict__ bsum) {
    __shared__ int s[64];
    int v = (threadIdx.x < NNODES_PAD / 1024) ? bsum[threadIdx.x] : 0;
    s[threadIdx.x] = v;
    __syncthreads();
    for (int d = 1; d < 64; d <<= 1) {
        int t = (threadIdx.x >= d) ? s[threadIdx.x - d] : 0;
        __syncthreads();
        s[threadIdx.x] += t;
        __syncthreads();
    }
    bsum[threadIdx.x] = s[threadIdx.x] - v;
}

__global__ __launch_bounds__(1024) void scan3(int* __restrict__ offs,
                                              const int* __restrict__ bsum,
                                              int* __restrict__ cursor) {
    int i = blockIdx.x * 1024 + threadIdx.x;
    int v = offs[i] + bsum[blockIdx.x];
    offs[i] = v;
    cursor[i] = v;
}

// slotmap[e]=p (scatter map for feat)
__global__ __launch_bounds__(512) void scatter_kernel(const int* __restrict__ dst,
                                                      int* __restrict__ cursor,
                                                      int* __restrict__ slotmap) {
    int e = blockIdx.x * 512 + threadIdx.x;
    if (e < N_EDGES) {
        int p = atomicAdd(&cursor[dst[e]], 1);
        slotmap[e] = p;
    }
}

// ---------------------------------------------------------------------------
// feat kernel v12 = r9's proven (512,2) body + h[src]*w[rel] + norm fold.
// Natural edge order, persistent compact-B LDS (79872 B, one barrier),
// 8 waves grid-stride, A+rel+src+dst prefetched one tile ahead; feat is
// initialized with h[src]*w[rel] (56 quarter-wave-segment loads issued before
// the MFMA loop -> complete under its shadow); complete message
// (h*w + attfeat)*norm scattered bf16 to dst-sorted slots. agg = pure stream.
// ---------------------------------------------------------------------------
template<bool TOWS>
__global__ __launch_bounds__(512, 2) void feat_kernel(
        const float* __restrict__ efeat, const int* __restrict__ rel,
        const unsigned short* __restrict__ Bimg, const float* __restrict__ attn,
        const float* __restrict__ h, const float* __restrict__ weight,
        const float* __restrict__ norm, const int* __restrict__ src,
        const int* __restrict__ dst, const int* __restrict__ slotmap,
        float* __restrict__ out, unsigned short* __restrict__ msgws,
        int ntiles) {   // ntiles = N_EDGES / 16

    __shared__ __align__(16) unsigned short Blds[BROWS * 128];   // 79872 B

    const int tid = threadIdx.x;
    {
        const int4* sp = reinterpret_cast<const int4*>(Bimg);
        int4* dp = reinterpret_cast<int4*>(Blds);
        for (int i = tid; i < BROWS * 128 / 8; i += 512) dp[i] = sp[i];
    }
    __syncthreads();   // the only barrier

    const int wave = tid >> 6, lane = tid & 63;
    const int lrow = lane & 15, lk = lane >> 4;
    const int gstride = gridDim.x * WPB;
    int tile = blockIdx.x * WPB + wave;
    if (tile >= ntiles) return;

    const char* Bc = reinterpret_cast<const char*>(Blds);
    int bkt[4];
#pragma unroll
    for (int kt = 0; kt < 4; ++kt)
        bkt[kt] = lrow * 256 + ((kt * 64 + lk * 16) ^ ((lrow & 7) << 4));

    float4 pa[8];
    int prl[4], psr[4], pdd[4];

    auto prefetch = [&](int t) {
        int eb = t * 16;
        const float* ap = efeat + (size_t)(eb + lrow) * IN_FEAT;
#pragma unroll
        for (int kt = 0; kt < 4; ++kt) {
            int k0 = kt * 32 + lk * 4, k1 = k0 + 16;
            pa[kt * 2]     = (k0 + 4 <= IN_FEAT) ? *reinterpret_cast<const float4*>(ap + k0)
                                                 : make_float4(0.f, 0.f, 0.f, 0.f);
            pa[kt * 2 + 1] = (k1 + 4 <= IN_FEAT) ? *reinterpret_cast<const float4*>(ap + k1)
                                                 : make_float4(0.f, 0.f, 0.f, 0.f);
        }
        const int* rp = rel + eb + lk * 4;
        const int* sp = src + eb + lk * 4;
        const int* dp = dst + eb + lk * 4;
#pragma unroll
        for (int r = 0; r < 4; ++r) { prl[r] = rp[r]; psr[r] = sp[r]; pdd[r] = dp[r]; }
    };

    prefetch(tile);

    while (true) {
        const int cur = tile;
        const int tb = cur * 16;

        // ---- consume prefetched A ----
        short8 afrag[4];
#pragma unroll
        for (int kt = 0; kt < 4; ++kt) {
            float4 va = pa[kt * 2], vb = pa[kt * 2 + 1];
            afrag[kt][0] = (short)f2bf(va.x); afrag[kt][1] = (short)f2bf(va.y);
            afrag[kt][2] = (short)f2bf(va.z); afrag[kt][3] = (short)f2bf(va.w);
            afrag[kt][4] = (short)f2bf(vb.x); afrag[kt][5] = (short)f2bf(vb.y);
            afrag[kt][6] = (short)f2bf(vb.z); afrag[kt][7] = (short)f2bf(vb.w);
        }
        int aoff[4], hoff[4], woff[4];
        float nm[4];
#pragma unroll
        for (int r = 0; r < 4; ++r) {
            aoff[r] = prl[r] * (NUM_HEADS * OUT_FEAT);
            woff[r] = prl[r] * OUT_FEAT;
            hoff[r] = psr[r] * IN_FEAT;
            nm[r]   = norm[pdd[r]];
        }
        int slot_r[4], dd_r[4];
        if (TOWS) {
#pragma unroll
            for (int r = 0; r < 4; ++r) slot_r[r] = slotmap[tb + lk * 4 + r];
        } else {
#pragma unroll
            for (int r = 0; r < 4; ++r) dd_r[r] = pdd[r];
        }

        // ---- prefetch next tile ----
        int next = tile + gstride;
        bool more = next < ntiles;
        prefetch(more ? next : cur);

        // ---- feat init = h[src]*w[rel]; loads overlap the MFMA loop below ----
        float feat[NT_O][4];
#pragma unroll
        for (int nt = 0; nt < NT_O; ++nt) {
            int o = nt * 16 + lrow;
#pragma unroll
            for (int r = 0; r < 4; ++r)
                feat[nt][r] = (o < OUT_FEAT) ? h[hoff[r] + o] * weight[woff[r] + o] : 0.f;
        }

        // ---- 3 heads x 7 col-tiles x K=128, B from LDS ----
#pragma unroll 1
        for (int hh = 0; hh < NUM_HEADS; ++hh) {
            const char* Bh = Bc + hh * HSTRIDE;
#pragma unroll
            for (int nt = 0; nt < NT_O; ++nt) {
                f32x4 acc = (f32x4){0.f, 0.f, 0.f, 0.f};
#pragma unroll
                for (int kt = 0; kt < 4; ++kt) {
                    short8 bfrag = *reinterpret_cast<const short8*>(
                        Bh + bkt[kt] + nt * 4096);
                    acc = __builtin_amdgcn_mfma_f32_16x16x32_bf16(afrag[kt], bfrag, acc, 0, 0, 0);
                }
                int o = nt * 16 + lrow;
                if (o < OUT_FEAT) {
                    int oo = hh * OUT_FEAT + o;
#pragma unroll
                    for (int r = 0; r < 4; ++r) {
                        float v = acc[r] * attn[aoff[r] + oo];
                        feat[nt][r] += (v > 0.f) ? v : 0.2f * v;
                    }
                }
            }
        }

        if (TOWS) {
            // complete message * norm -> dst-sorted slots (32 B quarter-wave segs)
#pragma unroll
            for (int nt = 0; nt < NT_O; ++nt) {
                int o = nt * 16 + lrow;
                if (o < OUT_FEAT) {
#pragma unroll
                    for (int r = 0; r < 4; ++r)
                        msgws[(size_t)slot_r[r] * MSGW + o] = f2bf(feat[nt][r] * nm[r]);
                }
            }
        } else {
            // fallback: atomic scatter-add of the complete message
#pragma unroll
            for (int nt = 0; nt < NT_O; ++nt) {
                int o = nt * 16 + lrow;
                if (o < OUT_FEAT) {
#pragma unroll
                    for (int r = 0; r < 4; ++r)
                        atomicAdd(&out[(size_t)dd_r[r] * OUT_FEAT + o],
                                  feat[nt][r] * nm[r]);
                }
            }
        }

        if (!more) break;
        tile = next;
    }
}

// ---------------------------------------------------------------------------
// agg kernel: one wave per node; msg rows CONTIGUOUS in slot order -> pure
// streaming segmented sum (h*w and norm already folded). out += sum.
// ---------------------------------------------------------------------------
__global__ __launch_bounds__(256, 4) void agg_kernel(
        const unsigned short* __restrict__ msgws, const int* __restrict__ offs,
        const int* __restrict__ cnt, float* __restrict__ out) {
    int wv = threadIdx.x >> 6, lane = threadIdx.x & 63;
    int n = blockIdx.x * 4 + wv;
    if (n >= N_NODES) return;
    int start = offs[n], deg = cnt[n];
    if (deg == 0 || lane >= OUT_FEAT / 2) return;
    const unsigned* mp = reinterpret_cast<const unsigned*>(msgws);
    float ax = 0.f, ay = 0.f;
    int k = start, end = start + deg;
    for (; k + 4 <= end; k += 4) {
        unsigned u0 = mp[(size_t)k * (MSGW / 2) + lane];
        unsigned u1 = mp[(size_t)(k + 1) * (MSGW / 2) + lane];
        unsigned u2 = mp[(size_t)(k + 2) * (MSGW / 2) + lane];
        unsigned u3 = mp[(size_t)(k + 3) * (MSGW / 2) + lane];
        ax += bf2f(u0 & 0xffffu) + bf2f(u1 & 0xffffu) + bf2f(u2 & 0xffffu) + bf2f(u3 & 0xffffu);
        ay += bf2f(u0 >> 16) + bf2f(u1 >> 16) + bf2f(u2 >> 16) + bf2f(u3 >> 16);
    }
    for (; k < end; ++k) {
        unsigned u0 = mp[(size_t)k * (MSGW / 2) + lane];
        ax += bf2f(u0 & 0xffffu);
        ay += bf2f(u0 >> 16);
    }
    float2* op = reinterpret_cast<float2*>(out + (size_t)n * OUT_FEAT) + lane;
    float2 curv = *op;
    curv.x += ax; curv.y += ay;
    *op = curv;
}

extern "C" void kernel_launch(void* const* d_in, const int* in_sizes, int n_in,
                              void* d_out, int out_size, void* d_ws, size_t ws_size,
                              hipStream_t stream) {
    const float* h      = (const float*)d_in[0];
    const float* efeat  = (const float*)d_in[1];
    const float* norm   = (const float*)d_in[2];
    const float* weight = (const float*)d_in[3];
    const float* attn   = (const float*)d_in[4];
    const float* fc_w   = (const float*)d_in[5];
    const float* loop_w = (const float*)d_in[6];
    const int*   rel    = (const int*)d_in[7];
    const int*   src    = (const int*)d_in[8];
    const int*   dst    = (const int*)d_in[9];
    float* out = (float*)d_out;

    char* ws = (char*)d_ws;
    unsigned short* Bimg  = (unsigned short*)(ws + WS_B);
    unsigned short* LWimg = (unsigned short*)(ws + WS_LW);
    int* cnt     = (int*)(ws + WS_CNT);
    int* offs    = (int*)(ws + WS_OFFS);
    int* cursor  = (int*)(ws + WS_CURSOR);
    int* bsum    = (int*)(ws + WS_BSUM);
    int* slotmap = (int*)(ws + WS_SLOT);
    unsigned short* msgws = (unsigned short*)(ws + WS_MSG);

    build_B<<<(BROWS * 16 + 255) / 256, 256, 0, stream>>>(fc_w, Bimg);
    build_LW<<<(NPH * 16 + 255) / 256, 256, 0, stream>>>(loop_w, LWimg);
    loop_gemm<<<(N_NODES + MB - 1) / MB, 512, 0, stream>>>(h, LWimg, out);

    const int ntiles = N_EDGES / 16;   // 50000

    if (ws_size >= (size_t)WS_NEEDED) {
        hipMemsetAsync(cnt, 0, NNODES_PAD * sizeof(int), stream);
        hist_kernel<<<(N_EDGES + 511) / 512, 512, 0, stream>>>(dst, cnt);
        scan1<<<NNODES_PAD / 1024, 1024, 0, stream>>>(cnt, offs, bsum);
        scan2<<<1, 64, 0, stream>>>(bsum);
        scan3<<<NNODES_PAD / 1024, 1024, 0, stream>>>(offs, bsum, cursor);
        scatter_kernel<<<(N_EDGES + 511) / 512, 512, 0, stream>>>(dst, cursor, slotmap);

        feat_kernel<true><<<512, 512, 0, stream>>>(
            efeat, rel, Bimg, attn, h, weight, norm, src, dst, slotmap,
            out, msgws, ntiles);
        agg_kernel<<<(N_NODES + 3) / 4, 256, 0, stream>>>(msgws, offs, cnt, out);
    } else {
        feat_kernel<false><<<512, 512, 0, stream>>>(
            efeat, rel, Bimg, attn, h, weight, norm, src, dst, nullptr,
            out, msgws, ntiles);
    }
}

// Round 13
// 400.074 us; speedup vs baseline: 1.7557x; 1.0042x over previous
//
#include <hip/hip_runtime.h>
#include <hip/hip_bf16.h>

#define N_NODES 50000
#define N_EDGES 800000
#define IN_FEAT 100
#define OUT_FEAT 100
#define NUM_RELS 200
#define NUM_HEADS 3

#define KP 128          // padded K (100 -> 128)
#define NPH 112         // per-head padded N for MFMA tiling (7*16)
#define MB  128         // node-rows per block (loop_gemm)
#define NT_O 7          // NPH/16
#define WPB 8           // waves per feat block (512 threads)
#define MSGW 100        // msg row width (ushorts) = 200 B
#define BROWS 300       // compact B rows: 3*100, NO guard (clamped nt=6 reads)
#define HSTRIDE 25600   // bytes per head in compact B (100 rows * 256 B)

// ---- workspace layout (bytes) ----
#define WS_B       0u           // compact fc_w^T bf16 image: 76800
#define WS_LW      86016u       // loop_w^T bf16 image (linear): 28672
#define WS_CNT     114688u      // 50176 ints
#define WS_OFFS    315392u
#define WS_CURSOR  516096u
#define WS_BSUM    716800u      // 64 ints
#define WS_SLOT    717056u      // slotmap[e]: 800000 ints
#define WS_MSG     7117056u     // bf16 msg rows, 100 ushorts (200 B) each, slot order
#define WS_NEEDED  167117056u
#define NNODES_PAD 50176        // 49*1024

typedef __attribute__((ext_vector_type(8))) short short8;
typedef __attribute__((ext_vector_type(4))) float f32x4;

__device__ __forceinline__ unsigned short f2bf(float f) {
    unsigned u = __builtin_bit_cast(unsigned, f);
    unsigned r = u + 0x7FFFu + ((u >> 16) & 1u);
    return (unsigned short)(r >> 16);
}
__device__ __forceinline__ float bf2f(unsigned hs) {
    return __builtin_bit_cast(float, hs << 16);
}

// ---------------------------------------------------------------------------
// Compact B = fc_w^T bf16: 300 rows of 256 B (75 KiB -> two blocks/CU fit).
// Row n = head*100 + nl, XOR-swizzled:
// granule g at byte n*256 + ((g*16) ^ ((nl&7)<<4)); elem j in [0,8):
// k = kt*32 + (j>>2)*16 + g4*4 + (j&3). nt=6 fragment reads for heads 0/1
// alias into the next head's real rows (garbage feeds only discarded cols);
// head 2's nt=6 reads are CLAMPED to row 299 in the feat kernel.
// ---------------------------------------------------------------------------
__global__ __launch_bounds__(256) void build_B(const float* __restrict__ fc_w,
                                               unsigned short* __restrict__ Bws) {
    int idx = blockIdx.x * 256 + threadIdx.x;     // granule id: n*16 + g
    if (idx >= BROWS * 16) return;
    int n = idx >> 4, g = idx & 15;
    int head = n / 100, nl = n - head * 100;
    int kt = g >> 2, g4 = g & 3;
    unsigned p[4];
#pragma unroll
    for (int half = 0; half < 2; ++half) {
#pragma unroll
        for (int jp = 0; jp < 2; ++jp) {
            int k_lo = kt * 32 + half * 16 + g4 * 4 + jp * 2;
            int k_hi = k_lo + 1;
            float vlo = (k_lo < IN_FEAT)
                      ? fc_w[k_lo * (OUT_FEAT * NUM_HEADS) + head * OUT_FEAT + nl] : 0.f;
            float vhi = (k_hi < IN_FEAT)
                      ? fc_w[k_hi * (OUT_FEAT * NUM_HEADS) + head * OUT_FEAT + nl] : 0.f;
            p[half * 2 + jp] = (unsigned)f2bf(vlo) | ((unsigned)f2bf(vhi) << 16);
        }
    }
    unsigned off = (unsigned)(n * 256) + (((unsigned)(g * 16)) ^ (((unsigned)(nl & 7)) << 4));
    *reinterpret_cast<int4*>(reinterpret_cast<char*>(Bws) + off) =
        make_int4((int)p[0], (int)p[1], (int)p[2], (int)p[3]);
}

// loop_w^T bf16 image, LINEAR (read from L2 by loop_gemm fragments)
__global__ __launch_bounds__(256) void build_LW(const float* __restrict__ loop_w,
                                                unsigned short* __restrict__ LWws) {
    int idx = blockIdx.x * 256 + threadIdx.x;
    if (idx >= NPH * 16) return;
    int nl = idx >> 4, g = idx & 15;
    int kt = g >> 2, g4 = g & 3;
    unsigned p[4];
#pragma unroll
    for (int half = 0; half < 2; ++half) {
#pragma unroll
        for (int jp = 0; jp < 2; ++jp) {
            int k_lo = kt * 32 + half * 16 + g4 * 4 + jp * 2;
            int k_hi = k_lo + 1;
            float vlo = (k_lo < IN_FEAT && nl < OUT_FEAT) ? loop_w[k_lo * OUT_FEAT + nl] : 0.f;
            float vhi = (k_hi < IN_FEAT && nl < OUT_FEAT) ? loop_w[k_hi * OUT_FEAT + nl] : 0.f;
            p[half * 2 + jp] = (unsigned)f2bf(vlo) | ((unsigned)f2bf(vhi) << 16);
        }
    }
    reinterpret_cast<int4*>(LWws)[idx] = make_int4((int)p[0], (int)p[1], (int)p[2], (int)p[3]);
}

// ---------------------------------------------------------------------------
// Self-loop GEMM: out = h @ loop_w. Zero LDS/barriers; LW from L2.
// ---------------------------------------------------------------------------
__global__ __launch_bounds__(512, 2) void loop_gemm(const float* __restrict__ h,
                                                    const unsigned short* __restrict__ LWimg,
                                                    float* __restrict__ out) {
    const int tid = threadIdx.x;
    const int wave = tid >> 6, lane = tid & 63;
    const int lrow = lane & 15, lk = lane >> 4;
    const int rbase = blockIdx.x * MB;
    const int grow = rbase + wave * 16 + lrow;
    const bool ok = grow < N_NODES;
    const float* ap = h + (size_t)grow * IN_FEAT;

    short8 afrag[4];
#pragma unroll
    for (int kt = 0; kt < 4; ++kt) {
        int k0 = kt * 32 + lk * 4, k1 = k0 + 16;
        float4 va = (ok && k0 + 4 <= IN_FEAT) ? *reinterpret_cast<const float4*>(ap + k0)
                                              : make_float4(0.f, 0.f, 0.f, 0.f);
        float4 vb = (ok && k1 + 4 <= IN_FEAT) ? *reinterpret_cast<const float4*>(ap + k1)
                                              : make_float4(0.f, 0.f, 0.f, 0.f);
        afrag[kt][0] = (short)f2bf(va.x); afrag[kt][1] = (short)f2bf(va.y);
        afrag[kt][2] = (short)f2bf(va.z); afrag[kt][3] = (short)f2bf(va.w);
        afrag[kt][4] = (short)f2bf(vb.x); afrag[kt][5] = (short)f2bf(vb.y);
        afrag[kt][6] = (short)f2bf(vb.z); afrag[kt][7] = (short)f2bf(vb.w);
    }

#pragma unroll
    for (int nt = 0; nt < NT_O; ++nt) {
        f32x4 acc = (f32x4){0.f, 0.f, 0.f, 0.f};
#pragma unroll
        for (int kt = 0; kt < 4; ++kt) {
            short8 bfrag = *reinterpret_cast<const short8*>(
                LWimg + ((nt * 16 + lrow) * KP + kt * 32 + lk * 8));
            acc = __builtin_amdgcn_mfma_f32_16x16x32_bf16(afrag[kt], bfrag, acc, 0, 0, 0);
        }
        int o = nt * 16 + lrow;
        if (o < OUT_FEAT) {
#pragma unroll
            for (int r = 0; r < 4; ++r) {
                int crow = rbase + wave * 16 + lk * 4 + r;
                if (crow < N_NODES) out[(size_t)crow * OUT_FEAT + o] = acc[r];
            }
        }
    }
}

// ---------------------------------------------------------------------------
// CSR construction
// ---------------------------------------------------------------------------
__global__ __launch_bounds__(512) void hist_kernel(const int* __restrict__ dst,
                                                   int* __restrict__ cnt) {
    int e = blockIdx.x * 512 + threadIdx.x;
    if (e < N_EDGES) atomicAdd(&cnt[dst[e]], 1);
}

__global__ __launch_bounds__(1024) void scan1(const int* __restrict__ cnt,
                                              int* __restrict__ offs,
                                              int* __restrict__ bsum) {
    __shared__ int s[1024];
    int i = blockIdx.x * 1024 + threadIdx.x;
    int v = (i < N_NODES) ? cnt[i] : 0;
    s[threadIdx.x] = v;
    __syncthreads();
    for (int d = 1; d < 1024; d <<= 1) {
        int t = (threadIdx.x >= d) ? s[threadIdx.x - d] : 0;
        __syncthreads();
        s[threadIdx.x] += t;
        __syncthreads();
    }
    offs[i] = s[threadIdx.x] - v;
    if (threadIdx.x == 1023) bsum[blockIdx.x] = s[1023];
}

__global__ __launch_bounds__(64) void scan2(int* __restrict__ bsum) {
    __shared__ int s[64];
    int v = (threadIdx.x < NNODES_PAD / 1024) ? bsum[threadIdx.x] : 0;
    s[threadIdx.x] = v;
    __syncthreads();
    for (int d = 1; d < 64; d <<= 1) {
        int t = (threadIdx.x >= d) ? s[threadIdx.x - d] : 0;
        __syncthreads();
        s[threadIdx.x] += t;
        __syncthreads();
    }
    bsum[threadIdx.x] = s[threadIdx.x] - v;
}

__global__ __launch_bounds__(1024) void scan3(int* __restrict__ offs,
                                              const int* __restrict__ bsum,
                                              int* __restrict__ cursor) {
    int i = blockIdx.x * 1024 + threadIdx.x;
    int v = offs[i] + bsum[blockIdx.x];
    offs[i] = v;
    cursor[i] = v;
}

// slotmap[e]=p (scatter map for feat)
__global__ __launch_bounds__(512) void scatter_kernel(const int* __restrict__ dst,
                                                      int* __restrict__ cursor,
                                                      int* __restrict__ slotmap) {
    int e = blockIdx.x * 512 + threadIdx.x;
    if (e < N_EDGES) {
        int p = atomicAdd(&cursor[dst[e]], 1);
        slotmap[e] = p;
    }
}

// ---------------------------------------------------------------------------
// feat kernel v13 = r12 body, LDS shrunk to 75 KiB (BROWS 300, guard rows
// replaced by a lane-constant clamped address for head2/nt=6) so TWO 512-thread
// blocks fit per CU (153600 B <= 160 KiB with slack) -> 16 waves/CU.
// Natural edge order, persistent compact-B LDS (one barrier), 8 waves
// grid-stride, A+rel+src+dst prefetched one tile ahead; feat initialized with
// h[src]*w[rel]; complete message (h*w + attfeat)*norm scattered bf16 to
// dst-sorted slots. agg = pure stream.
// ---------------------------------------------------------------------------
template<bool TOWS>
__global__ __launch_bounds__(512, 2) void feat_kernel(
        const float* __restrict__ efeat, const int* __restrict__ rel,
        const unsigned short* __restrict__ Bimg, const float* __restrict__ attn,
        const float* __restrict__ h, const float* __restrict__ weight,
        const float* __restrict__ norm, const int* __restrict__ src,
        const int* __restrict__ dst, const int* __restrict__ slotmap,
        float* __restrict__ out, unsigned short* __restrict__ msgws,
        int ntiles) {   // ntiles = N_EDGES / 16

    __shared__ __align__(16) unsigned short Blds[BROWS * 128];   // 76800 B

    const int tid = threadIdx.x;
    {
        const int4* sp = reinterpret_cast<const int4*>(Bimg);
        int4* dp = reinterpret_cast<int4*>(Blds);
        for (int i = tid; i < BROWS * 128 / 8; i += 512) dp[i] = sp[i];
    }
    __syncthreads();   // the only barrier

    const int wave = tid >> 6, lane = tid & 63;
    const int lrow = lane & 15, lk = lane >> 4;
    const int gstride = gridDim.x * WPB;
    int tile = blockIdx.x * WPB + wave;
    if (tile >= ntiles) return;

    const char* Bc = reinterpret_cast<const char*>(Blds);
    int bkt[4], bkt6[4];
    const int mlr = (lrow < 3) ? lrow : 3;   // clamped lane-row for head2/nt=6
#pragma unroll
    for (int kt = 0; kt < 4; ++kt) {
        bkt[kt]  = lrow * 256 + ((kt * 64 + lk * 16) ^ ((lrow & 7) << 4));
        // absolute byte offset of row (296+mlr); swizzle key (96+mlr)&7 == mlr
        bkt6[kt] = (296 + mlr) * 256 + ((kt * 64 + lk * 16) ^ (mlr << 4));
    }

    float4 pa[8];
    int prl[4], psr[4], pdd[4];

    auto prefetch = [&](int t) {
        int eb = t * 16;
        const float* ap = efeat + (size_t)(eb + lrow) * IN_FEAT;
#pragma unroll
        for (int kt = 0; kt < 4; ++kt) {
            int k0 = kt * 32 + lk * 4, k1 = k0 + 16;
            pa[kt * 2]     = (k0 + 4 <= IN_FEAT) ? *reinterpret_cast<const float4*>(ap + k0)
                                                 : make_float4(0.f, 0.f, 0.f, 0.f);
            pa[kt * 2 + 1] = (k1 + 4 <= IN_FEAT) ? *reinterpret_cast<const float4*>(ap + k1)
                                                 : make_float4(0.f, 0.f, 0.f, 0.f);
        }
        const int* rp = rel + eb + lk * 4;
        const int* sp = src + eb + lk * 4;
        const int* dp = dst + eb + lk * 4;
#pragma unroll
        for (int r = 0; r < 4; ++r) { prl[r] = rp[r]; psr[r] = sp[r]; pdd[r] = dp[r]; }
    };

    prefetch(tile);

    while (true) {
        const int cur = tile;
        const int tb = cur * 16;

        // ---- consume prefetched A ----
        short8 afrag[4];
#pragma unroll
        for (int kt = 0; kt < 4; ++kt) {
            float4 va = pa[kt * 2], vb = pa[kt * 2 + 1];
            afrag[kt][0] = (short)f2bf(va.x); afrag[kt][1] = (short)f2bf(va.y);
            afrag[kt][2] = (short)f2bf(va.z); afrag[kt][3] = (short)f2bf(va.w);
            afrag[kt][4] = (short)f2bf(vb.x); afrag[kt][5] = (short)f2bf(vb.y);
            afrag[kt][6] = (short)f2bf(vb.z); afrag[kt][7] = (short)f2bf(vb.w);
        }
        int aoff[4], hoff[4], woff[4];
        float nm[4];
#pragma unroll
        for (int r = 0; r < 4; ++r) {
            aoff[r] = prl[r] * (NUM_HEADS * OUT_FEAT);
            woff[r] = prl[r] * OUT_FEAT;
            hoff[r] = psr[r] * IN_FEAT;
            nm[r]   = norm[pdd[r]];
        }
        int slot_r[4], dd_r[4];
        if (TOWS) {
#pragma unroll
            for (int r = 0; r < 4; ++r) slot_r[r] = slotmap[tb + lk * 4 + r];
        } else {
#pragma unroll
            for (int r = 0; r < 4; ++r) dd_r[r] = pdd[r];
        }

        // ---- prefetch next tile ----
        int next = tile + gstride;
        bool more = next < ntiles;
        prefetch(more ? next : cur);

        // ---- feat init = h[src]*w[rel]; loads overlap the MFMA loop below ----
        float feat[NT_O][4];
#pragma unroll
        for (int nt = 0; nt < NT_O; ++nt) {
            int o = nt * 16 + lrow;
#pragma unroll
            for (int r = 0; r < 4; ++r)
                feat[nt][r] = (o < OUT_FEAT) ? h[hoff[r] + o] * weight[woff[r] + o] : 0.f;
        }

        // ---- 3 heads x 7 col-tiles x K=128, B from LDS ----
#pragma unroll 1
        for (int hh = 0; hh < NUM_HEADS; ++hh) {
            const char* Bh = Bc + hh * HSTRIDE;
            const bool last = (hh == NUM_HEADS - 1);
#pragma unroll
            for (int nt = 0; nt < NT_O; ++nt) {
                f32x4 acc = (f32x4){0.f, 0.f, 0.f, 0.f};
#pragma unroll
                for (int kt = 0; kt < 4; ++kt) {
                    const char* addr = (nt == NT_O - 1 && last)
                                     ? (Bc + bkt6[kt])
                                     : (Bh + bkt[kt] + nt * 4096);
                    short8 bfrag = *reinterpret_cast<const short8*>(addr);
                    acc = __builtin_amdgcn_mfma_f32_16x16x32_bf16(afrag[kt], bfrag, acc, 0, 0, 0);
                }
                int o = nt * 16 + lrow;
                if (o < OUT_FEAT) {
                    int oo = hh * OUT_FEAT + o;
#pragma unroll
                    for (int r = 0; r < 4; ++r) {
                        float v = acc[r] * attn[aoff[r] + oo];
                        feat[nt][r] += (v > 0.f) ? v : 0.2f * v;
                    }
                }
            }
        }

        if (TOWS) {
            // complete message * norm -> dst-sorted slots (32 B quarter-wave segs)
#pragma unroll
            for (int nt = 0; nt < NT_O; ++nt) {
                int o = nt * 16 + lrow;
                if (o < OUT_FEAT) {
#pragma unroll
                    for (int r = 0; r < 4; ++r)
                        msgws[(size_t)slot_r[r] * MSGW + o] = f2bf(feat[nt][r] * nm[r]);
                }
            }
        } else {
            // fallback: atomic scatter-add of the complete message
#pragma unroll
            for (int nt = 0; nt < NT_O; ++nt) {
                int o = nt * 16 + lrow;
                if (o < OUT_FEAT) {
#pragma unroll
                    for (int r = 0; r < 4; ++r)
                        atomicAdd(&out[(size_t)dd_r[r] * OUT_FEAT + o],
                                  feat[nt][r] * nm[r]);
                }
            }
        }

        if (!more) break;
        tile = next;
    }
}

// ---------------------------------------------------------------------------
// agg kernel: one wave per node; msg rows CONTIGUOUS in slot order -> pure
// streaming segmented sum (h*w and norm already folded). out += sum.
// ---------------------------------------------------------------------------
__global__ __launch_bounds__(256, 4) void agg_kernel(
        const unsigned short* __restrict__ msgws, const int* __restrict__ offs,
        const int* __restrict__ cnt, float* __restrict__ out) {
    int wv = threadIdx.x >> 6, lane = threadIdx.x & 63;
    int n = blockIdx.x * 4 + wv;
    if (n >= N_NODES) return;
    int start = offs[n], deg = cnt[n];
    if (deg == 0 || lane >= OUT_FEAT / 2) return;
    const unsigned* mp = reinterpret_cast<const unsigned*>(msgws);
    float ax = 0.f, ay = 0.f;
    int k = start, end = start + deg;
    for (; k + 4 <= end; k += 4) {
        unsigned u0 = mp[(size_t)k * (MSGW / 2) + lane];
        unsigned u1 = mp[(size_t)(k + 1) * (MSGW / 2) + lane];
        unsigned u2 = mp[(size_t)(k + 2) * (MSGW / 2) + lane];
        unsigned u3 = mp[(size_t)(k + 3) * (MSGW / 2) + lane];
        ax += bf2f(u0 & 0xffffu) + bf2f(u1 & 0xffffu) + bf2f(u2 & 0xffffu) + bf2f(u3 & 0xffffu);
        ay += bf2f(u0 >> 16) + bf2f(u1 >> 16) + bf2f(u2 >> 16) + bf2f(u3 >> 16);
    }
    for (; k < end; ++k) {
        unsigned u0 = mp[(size_t)k * (MSGW / 2) + lane];
        ax += bf2f(u0 & 0xffffu);
        ay += bf2f(u0 >> 16);
    }
    float2* op = reinterpret_cast<float2*>(out + (size_t)n * OUT_FEAT) + lane;
    float2 curv = *op;
    curv.x += ax; curv.y += ay;
    *op = curv;
}

extern "C" void kernel_launch(void* const* d_in, const int* in_sizes, int n_in,
                              void* d_out, int out_size, void* d_ws, size_t ws_size,
                              hipStream_t stream) {
    const float* h      = (const float*)d_in[0];
    const float* efeat  = (const float*)d_in[1];
    const float* norm   = (const float*)d_in[2];
    const float* weight = (const float*)d_in[3];
    const float* attn   = (const float*)d_in[4];
    const float* fc_w   = (const float*)d_in[5];
    const float* loop_w = (const float*)d_in[6];
    const int*   rel    = (const int*)d_in[7];
    const int*   src    = (const int*)d_in[8];
    const int*   dst    = (const int*)d_in[9];
    float* out = (float*)d_out;

    char* ws = (char*)d_ws;
    unsigned short* Bimg  = (unsigned short*)(ws + WS_B);
    unsigned short* LWimg = (unsigned short*)(ws + WS_LW);
    int* cnt     = (int*)(ws + WS_CNT);
    int* offs    = (int*)(ws + WS_OFFS);
    int* cursor  = (int*)(ws + WS_CURSOR);
    int* bsum    = (int*)(ws + WS_BSUM);
    int* slotmap = (int*)(ws + WS_SLOT);
    unsigned short* msgws = (unsigned short*)(ws + WS_MSG);

    build_B<<<(BROWS * 16 + 255) / 256, 256, 0, stream>>>(fc_w, Bimg);
    build_LW<<<(NPH * 16 + 255) / 256, 256, 0, stream>>>(loop_w, LWimg);
    loop_gemm<<<(N_NODES + MB - 1) / MB, 512, 0, stream>>>(h, LWimg, out);

    const int ntiles = N_EDGES / 16;   // 50000

    if (ws_size >= (size_t)WS_NEEDED) {
        hipMemsetAsync(cnt, 0, NNODES_PAD * sizeof(int), stream);
        hist_kernel<<<(N_EDGES + 511) / 512, 512, 0, stream>>>(dst, cnt);
        scan1<<<NNODES_PAD / 1024, 1024, 0, stream>>>(cnt, offs, bsum);
        scan2<<<1, 64, 0, stream>>>(bsum);
        scan3<<<NNODES_PAD / 1024, 1024, 0, stream>>>(offs, bsum, cursor);
        scatter_kernel<<<(N_EDGES + 511) / 512, 512, 0, stream>>>(dst, cursor, slotmap);

        feat_kernel<true><<<512, 512, 0, stream>>>(
            efeat, rel, Bimg, attn, h, weight, norm, src, dst, slotmap,
            out, msgws, ntiles);
        agg_kernel<<<(N_NODES + 3) / 4, 256, 0, stream>>>(msgws, offs, cnt, out);
    } else {
        feat_kernel<false><<<512, 512, 0, stream>>>(
            efeat, rel, Bimg, attn, h, weight, norm, src, dst, nullptr,
            out, msgws, ntiles);
    }
}